// Round 5
// baseline (7588.634 us; speedup 1.0000x reference)
//
#include <hip/hip_runtime.h>
#include <math.h>

#define T_LEN 512
#define BATCH 64
#define HID 128
#define G4 512   // 4*HID

// bf16-packed decoder weight block (elements)
#define OFF_WQ2   0        // Wq            128x128
#define OFF_WXO   16384    // Wih0[:,0:128] 512x128
#define OFF_WXC   81920    // Wih0[:,128:]@Ow fused  512x128
#define OFF_WHH0b 147456   // Whh0          512x128
#define OFF_WIH1b 212992   // Wih1          512x128
#define OFF_WHH1b 278528   // Whh1          512x128
#define W2_TOTAL  344064

__device__ __forceinline__ float sigf(float x) { return 1.0f / (1.0f + __expf(-x)); }

__device__ __forceinline__ unsigned short f2bf(float x) {
    unsigned u = __float_as_uint(x);
    unsigned r = (u + 0x7fffu + ((u >> 16) & 1u)) >> 16;
    return (unsigned short)r;
}

__device__ __forceinline__ void cvt8(uint4 u, float f[8]) {
    f[0] = __uint_as_float(u.x << 16); f[1] = __uint_as_float(u.x & 0xffff0000u);
    f[2] = __uint_as_float(u.y << 16); f[3] = __uint_as_float(u.y & 0xffff0000u);
    f[4] = __uint_as_float(u.z << 16); f[5] = __uint_as_float(u.z & 0xffff0000u);
    f[6] = __uint_as_float(u.w << 16); f[7] = __uint_as_float(u.w & 0xffff0000u);
}

// ---------------------------------------------------------------------------
// C[M,N] = A[M,K] @ W[N,K]^T + bias[N]   (fp32, 128x128 tile, 8x8 microtile)
// ---------------------------------------------------------------------------
__global__ __launch_bounds__(256) void gemm_bias(
    const float* __restrict__ A, const float* __restrict__ W,
    const float* __restrict__ bias, float* __restrict__ C,
    int M, int N, int K)
{
    __shared__ __align__(16) float As[16][128];
    __shared__ __align__(16) float Ws[16][128];
    const int tid = threadIdx.x;
    const int m0 = blockIdx.y * 128;
    const int n0 = blockIdx.x * 128;
    const int tx = tid & 15, ty = tid >> 4;
    const int lrow = tid >> 1, lk = (tid & 1) * 8;
    float acc[8][8] = {};
    for (int k0 = 0; k0 < K; k0 += 16) {
        const float* Ap = A + (size_t)(m0 + lrow) * K + k0 + lk;
        const float* Wp = W + (size_t)(n0 + lrow) * K + k0 + lk;
        float4 a0 = *(const float4*)Ap;
        float4 a1 = *(const float4*)(Ap + 4);
        float4 w0 = *(const float4*)Wp;
        float4 w1 = *(const float4*)(Wp + 4);
        __syncthreads();
        As[lk+0][lrow]=a0.x; As[lk+1][lrow]=a0.y; As[lk+2][lrow]=a0.z; As[lk+3][lrow]=a0.w;
        As[lk+4][lrow]=a1.x; As[lk+5][lrow]=a1.y; As[lk+6][lrow]=a1.z; As[lk+7][lrow]=a1.w;
        Ws[lk+0][lrow]=w0.x; Ws[lk+1][lrow]=w0.y; Ws[lk+2][lrow]=w0.z; Ws[lk+3][lrow]=w0.w;
        Ws[lk+4][lrow]=w1.x; Ws[lk+5][lrow]=w1.y; Ws[lk+6][lrow]=w1.z; Ws[lk+7][lrow]=w1.w;
        __syncthreads();
        #pragma unroll
        for (int kk = 0; kk < 16; ++kk) {
            float4 av0 = *(const float4*)&As[kk][ty*8];
            float4 av1 = *(const float4*)&As[kk][ty*8+4];
            float4 wv0 = *(const float4*)&Ws[kk][tx*8];
            float4 wv1 = *(const float4*)&Ws[kk][tx*8+4];
            float av[8] = {av0.x,av0.y,av0.z,av0.w,av1.x,av1.y,av1.z,av1.w};
            float wv[8] = {wv0.x,wv0.y,wv0.z,wv0.w,wv1.x,wv1.y,wv1.z,wv1.w};
            #pragma unroll
            for (int i = 0; i < 8; ++i)
                #pragma unroll
                for (int j = 0; j < 8; ++j)
                    acc[i][j] = fmaf(av[i], wv[j], acc[i][j]);
        }
    }
    float bj[8];
    #pragma unroll
    for (int j = 0; j < 8; ++j) bj[j] = bias[n0 + tx*8 + j];
    #pragma unroll
    for (int i = 0; i < 8; ++i) {
        float* cp = C + (size_t)(m0 + ty*8 + i) * N + n0 + tx*8;
        *(float4*)cp     = make_float4(acc[i][0]+bj[0], acc[i][1]+bj[1], acc[i][2]+bj[2], acc[i][3]+bj[3]);
        *(float4*)(cp+4) = make_float4(acc[i][4]+bj[4], acc[i][5]+bj[5], acc[i][6]+bj[6], acc[i][7]+bj[7]);
    }
}

// ---------------------------------------------------------------------------
// LSTM recurrence, one workgroup per batch element, with X prefetch.
// ---------------------------------------------------------------------------
__global__ __launch_bounds__(512) void lstm_rec(
    const float* __restrict__ X,
    const float* __restrict__ Whh,
    float* __restrict__ Hout)
{
    const int b = blockIdx.x;
    const int r = threadIdx.x;
    __shared__ __align__(16) float h_s[HID];
    __shared__ float gate_s[G4];
    float w[HID];
    #pragma unroll
    for (int k = 0; k < HID; k += 4) {
        float4 v = *(const float4*)(Whh + (size_t)r * HID + k);
        w[k] = v.x; w[k+1] = v.y; w[k+2] = v.z; w[k+3] = v.w;
    }
    float c = 0.f;
    if (r < HID) h_s[r] = 0.f;
    __syncthreads();
    float xv = X[(size_t)b * G4 + r];
    for (int t = 0; t < T_LEN; ++t) {
        float xnext = 0.f;
        if (t + 1 < T_LEN) xnext = X[(size_t)((t + 1) * BATCH + b) * G4 + r];
        float a0 = xv, a1 = 0.f, a2 = 0.f, a3 = 0.f;
        const float4* h4 = (const float4*)h_s;
        #pragma unroll
        for (int k = 0; k < HID/4; ++k) {
            float4 hv = h4[k];
            a0 = fmaf(w[4*k+0], hv.x, a0);
            a1 = fmaf(w[4*k+1], hv.y, a1);
            a2 = fmaf(w[4*k+2], hv.z, a2);
            a3 = fmaf(w[4*k+3], hv.w, a3);
        }
        gate_s[r] = (a0 + a1) + (a2 + a3);
        __syncthreads();
        if (r < HID) {
            float gi = gate_s[r], gf = gate_s[HID+r], gg = gate_s[2*HID+r], go = gate_s[3*HID+r];
            c = sigf(gf) * c + sigf(gi) * tanhf(gg);
            float h = sigf(go) * tanhf(c);
            h_s[r] = h;
            Hout[(size_t)(t * BATCH + b) * HID + r] = h;
        }
        __syncthreads();
        xv = xnext;
    }
}

// ---------------------------------------------------------------------------
// KV repack: KVf (t*B+b, 256) fp32 -> Kb[b][t][128] bf16, Vt[b][d][512] bf16
// ---------------------------------------------------------------------------
__global__ __launch_bounds__(256) void kv_pack(
    const float* __restrict__ KVf, unsigned short* __restrict__ Kb,
    unsigned short* __restrict__ Vt)
{
    const int b = blockIdx.x & 63, tc = blockIdx.x >> 6;
    const int t0 = tc * 128;
    __shared__ unsigned short tile[128][130];
    const int half = threadIdx.x >> 7;      // 0/1
    const int d = threadIdx.x & 127;
    for (int tt = 0; tt < 128; tt += 2) {
        int trow = tt + half;
        int t = t0 + trow;
        const float* src = KVf + ((size_t)t * BATCH + b) * 256;
        Kb[((size_t)b * T_LEN + t) * HID + d] = f2bf(src[d]);
        tile[trow][d] = f2bf(src[128 + d]);
    }
    __syncthreads();
    for (int dd = 0; dd < 128; dd += 2) {
        int drow = dd + half;
        int ts = threadIdx.x & 127;
        Vt[((size_t)b * HID + drow) * T_LEN + t0 + ts] = tile[ts][drow];
    }
}

// ---------------------------------------------------------------------------
// pack2: fp32 -> bf16 for all decoder weights except the fused W_xc block
// ---------------------------------------------------------------------------
__global__ __launch_bounds__(256) void pack2(
    const float* __restrict__ attn_in_w,
    const float* __restrict__ dWih0, const float* __restrict__ dWhh0,
    const float* __restrict__ dWih1, const float* __restrict__ dWhh1,
    unsigned short* __restrict__ Wb2)
{
    int i = blockIdx.x * 256 + threadIdx.x;
    if (i >= W2_TOTAL) return;
    if (i >= OFF_WXC && i < OFF_WHH0b) return;   // filled by fuse_wxc
    float v;
    if (i < OFF_WXO) v = attn_in_w[i];                       // Wq rows 0..127
    else if (i < OFF_WXC) {
        int j = i - OFF_WXO; v = dWih0[(size_t)(j >> 7) * 256 + (j & 127)];
    }
    else if (i < OFF_WIH1b) v = dWhh0[i - OFF_WHH0b];
    else if (i < OFF_WHH1b) v = dWih1[i - OFF_WIH1b];
    else                    v = dWhh1[i - OFF_WHH1b];
    Wb2[i] = f2bf(v);
}

// ---------------------------------------------------------------------------
// W_xc[r][c] = sum_j Wih0[r][128+j] * Ow[j][c]   (bf16 out)
// ---------------------------------------------------------------------------
__global__ __launch_bounds__(256) void fuse_wxc(
    const float* __restrict__ dWih0, const float* __restrict__ ow,
    unsigned short* __restrict__ Wb2)
{
    __shared__ float ow_s[128 * 128];
    for (int i = threadIdx.x; i < 16384; i += 256) ow_s[i] = ow[i];
    __syncthreads();
    const int r = blockIdx.x * 2 + (threadIdx.x >> 7);
    const int c = threadIdx.x & 127;
    const float* wr = dWih0 + (size_t)r * 256 + 128;
    float acc = 0.f;
    #pragma unroll 8
    for (int j = 0; j < 128; ++j) acc = fmaf(wr[j], ow_s[j * 128 + c], acc);
    Wb2[OFF_WXC + r * 128 + c] = f2bf(acc);
}

// b0'[r] = b0[r] + sum_j Wih0[r][128+j] * ob[j]
__global__ __launch_bounds__(128) void fuse_b0(
    const float* __restrict__ dWih0, const float* __restrict__ ob,
    const float* __restrict__ db0, float* __restrict__ b0p)
{
    int r = blockIdx.x * 128 + threadIdx.x;
    const float* wr = dWih0 + (size_t)r * 256 + 128;
    float acc = db0[r];
    #pragma unroll 8
    for (int j = 0; j < 128; ++j) acc = fmaf(wr[j], ob[j], acc);
    b0p[r] = acc;
}

// ---------------------------------------------------------------------------
// Decoder v5: one WG (1024 thr) per batch; ALL decoder weights in VGPRs;
// K LDS-resident; no cross-WG communication of any kind.
// Thread t: gate-row r = t>>1, half = t&1 (192 of [wxo|wxc|whh0], 128 of
// [wih1|whh1]).  x_s = [out|ctx|h0] (384 f32), x1_s = [h0|h1] (256 f32).
// ---------------------------------------------------------------------------
__global__ __launch_bounds__(1024, 1) void decoder5(
    const unsigned short* __restrict__ Kb, const unsigned short* __restrict__ Vt,
    const unsigned short* __restrict__ Wb2, const float* __restrict__ b0p,
    const float* __restrict__ attn_b, const float* __restrict__ b1,
    const float* __restrict__ lw, const float* __restrict__ lb,
    float* __restrict__ Y)
{
    extern __shared__ __align__(16) char dyn[];
    char* Kl = dyn;                               // 512x256B swizzled = 128 KiB
    const int b = blockIdx.x;
    const int tid = threadIdx.x;
    __shared__ __align__(16) float x_s[384];      // [out | ctx | h0]
    __shared__ __align__(16) float x1_s[256];     // [h0 | h1]
    __shared__ __align__(16) float q_s[HID];
    __shared__ __align__(16) float sc[4 * T_LEN];
    __shared__ float red[16];
    __shared__ __align__(16) float ctxp[8][HID];
    __shared__ float g_s[G4];
    __shared__ float hmax[4], hden[4];

    // ---- stage K (batch b) into LDS, swizzled ----
    {
        const unsigned short* Ksrc = Kb + (size_t)b * T_LEN * HID;
        for (int c = tid; c < T_LEN * HID / 8; c += 1024) {
            int t = c >> 4, k16 = c & 15;
            uint4 v = *(const uint4*)(Ksrc + c * 8);
            *(uint4*)(Kl + t * 256 + ((k16 * 16) ^ ((t & 7) << 4))) = v;
        }
    }
    // ---- pin weights in VGPRs (static indices only) ----
    const int r = tid >> 1, half = tid & 1;
    uint4 W0[24], W1[16];
    #pragma unroll
    for (int i = 0; i < 24; ++i) {
        int ge = half * 192 + i * 8;
        const unsigned short* src =
            (ge < 128) ? Wb2 + OFF_WXO   + (size_t)r * HID + ge
          : (ge < 256) ? Wb2 + OFF_WXC   + (size_t)r * HID + (ge - 128)
                       : Wb2 + OFF_WHH0b + (size_t)r * HID + (ge - 256);
        W0[i] = *(const uint4*)src;
    }
    #pragma unroll
    for (int i = 0; i < 16; ++i) {
        int ge = half * 128 + i * 8;
        const unsigned short* src =
            (ge < 128) ? Wb2 + OFF_WIH1b + (size_t)r * HID + ge
                       : Wb2 + OFF_WHH1b + (size_t)r * HID + (ge - 128);
        W1[i] = *(const uint4*)src;
    }
    const float b0r = b0p[r];
    const float b1r = b1[r];
    const int qrow = tid >> 3, qpart = tid & 7;
    uint4 wqa = *(const uint4*)(Wb2 + OFF_WQ2 + (size_t)qrow * HID + qpart * 16);
    uint4 wqb = *(const uint4*)(Wb2 + OFF_WQ2 + (size_t)qrow * HID + qpart * 16 + 8);
    const float bqv = attn_b[qrow];
    float c0 = 0.f, c1 = 0.f;
    if (tid < 384) x_s[tid] = 0.f;
    if (tid < 256) x1_s[tid] = 0.f;
    __syncthreads();
    const float scale = 0.17677669529663687f;     // 1/sqrt(32)
    const int g2 = tid >> 8, l2 = tid & 255;

    for (int step = 0; step < 64; ++step) {
        // ---- q = (Wq @ out + bq) * scale ; 8 threads per row ----
        {
            float f[8];
            const float* os = x_s + qpart * 16;
            float acc = 0.f;
            cvt8(wqa, f);
            acc += f[0]*os[0]+f[1]*os[1]+f[2]*os[2]+f[3]*os[3]
                 + f[4]*os[4]+f[5]*os[5]+f[6]*os[6]+f[7]*os[7];
            cvt8(wqb, f);
            acc += f[0]*os[8]+f[1]*os[9]+f[2]*os[10]+f[3]*os[11]
                 + f[4]*os[12]+f[5]*os[13]+f[6]*os[14]+f[7]*os[15];
            acc += __shfl_xor(acc, 1);
            acc += __shfl_xor(acc, 2);
            acc += __shfl_xor(acc, 4);
            if (qpart == 0) q_s[qrow] = (acc + bqv) * scale;
        }
        __syncthreads();
        // ---- scores from LDS K (swizzled); threads 0..511, t = tid ----
        if (tid < T_LEN) {
            const int t = tid;
            float acc[4] = {0.f, 0.f, 0.f, 0.f};
            #pragma unroll
            for (int k16 = 0; k16 < 16; ++k16) {
                uint4 u = *(const uint4*)(Kl + t * 256 + ((k16 * 16) ^ ((t & 7) << 4)));
                float f[8]; cvt8(u, f);
                float4 q0 = *(const float4*)(q_s + k16 * 8);
                float4 q1 = *(const float4*)(q_s + k16 * 8 + 4);
                acc[k16 >> 2] += f[0]*q0.x + f[1]*q0.y + f[2]*q0.z + f[3]*q0.w
                               + f[4]*q1.x + f[5]*q1.y + f[6]*q1.z + f[7]*q1.w;
            }
            #pragma unroll
            for (int h = 0; h < 4; ++h) sc[h * T_LEN + t] = acc[h];
        }
        __syncthreads();
        // ---- softmax: head g2 = tid>>8, each thread 2 elems ----
        float v0 = sc[g2 * T_LEN + l2], v1 = sc[g2 * T_LEN + 256 + l2];
        float mx = fmaxf(v0, v1);
        #pragma unroll
        for (int s = 32; s > 0; s >>= 1) mx = fmaxf(mx, __shfl_xor(mx, s, 64));
        if ((tid & 63) == 0) red[tid >> 6] = mx;
        __syncthreads();
        if (tid < 4) hmax[tid] = fmaxf(fmaxf(red[tid*4], red[tid*4+1]),
                                       fmaxf(red[tid*4+2], red[tid*4+3]));
        __syncthreads();
        const float hm = hmax[g2];
        float e0 = __expf(v0 - hm), e1 = __expf(v1 - hm);
        sc[g2 * T_LEN + l2] = e0;
        sc[g2 * T_LEN + 256 + l2] = e1;
        float ss = e0 + e1;
        #pragma unroll
        for (int s = 32; s > 0; s >>= 1) ss += __shfl_xor(ss, s, 64);
        if ((tid & 63) == 0) red[tid >> 6] = ss;
        __syncthreads();
        if (tid < 4) hden[tid] = red[tid*4] + red[tid*4+1] + red[tid*4+2] + red[tid*4+3];
        __syncthreads();
        // ---- ctx: d = tid&127, chunk = tid>>7 (8 chunks of 64 t) ----
        {
            const int d = tid & 127, ch = tid >> 7;
            const unsigned short* vr = Vt + ((size_t)b * HID + d) * T_LEN + ch * 64;
            const float* scr = sc + (d >> 5) * T_LEN + ch * 64;
            float acc = 0.f;
            #pragma unroll
            for (int k = 0; k < 64; k += 8) {
                float f[8]; cvt8(*(const uint4*)(vr + k), f);
                #pragma unroll
                for (int j = 0; j < 8; ++j) acc = fmaf(f[j], scr[k + j], acc);
            }
            ctxp[ch][d] = acc;
        }
        __syncthreads();
        if (tid < HID) {
            float cx = 0.f;
            #pragma unroll
            for (int ch = 0; ch < 8; ++ch) cx += ctxp[ch][tid];
            x_s[HID + tid] = cx / hden[tid >> 5];
        }
        __syncthreads();
        // ---- gates0: row r, half-slice of [out|ctx|h0] (384) ----
        {
            float acc = 0.f;
            #pragma unroll
            for (int i = 0; i < 24; ++i) {
                float f[8]; cvt8(W0[i], f);
                const float* xp = x_s + half * 192 + i * 8;
                acc += f[0]*xp[0]+f[1]*xp[1]+f[2]*xp[2]+f[3]*xp[3]
                     + f[4]*xp[4]+f[5]*xp[5]+f[6]*xp[6]+f[7]*xp[7];
            }
            acc += __shfl_xor(acc, 1);
            if (half == 0) g_s[r] = acc + b0r;
        }
        __syncthreads();
        if (tid < HID) {
            float gi = g_s[tid], gf = g_s[HID+tid], gg = g_s[2*HID+tid], go = g_s[3*HID+tid];
            c0 = sigf(gf) * c0 + sigf(gi) * tanhf(gg);
            float h = sigf(go) * tanhf(c0);
            x_s[256 + tid] = h;
            x1_s[tid] = h;
        }
        __syncthreads();
        // ---- gates1: row r, half-slice of [h0|h1] (256) ----
        {
            float acc = 0.f;
            #pragma unroll
            for (int i = 0; i < 16; ++i) {
                float f[8]; cvt8(W1[i], f);
                const float* xp = x1_s + half * 128 + i * 8;
                acc += f[0]*xp[0]+f[1]*xp[1]+f[2]*xp[2]+f[3]*xp[3]
                     + f[4]*xp[4]+f[5]*xp[5]+f[6]*xp[6]+f[7]*xp[7];
            }
            acc += __shfl_xor(acc, 1);
            if (half == 0) g_s[r] = acc + b1r;
        }
        __syncthreads();
        if (tid < HID) {
            float gi = g_s[tid], gf = g_s[HID+tid], gg = g_s[2*HID+tid], go = g_s[3*HID+tid];
            c1 = sigf(gf) * c1 + sigf(gi) * tanhf(gg);
            float h = sigf(go) * tanhf(c1);
            x1_s[HID + tid] = h;
            x_s[tid] = fmaxf(h, 0.f);
        }
        __syncthreads();
        // ---- y = out @ lw.T + lb ; 8 threads per output row ----
        if (tid < 24) {
            const int row = tid >> 3, part = tid & 7;
            const float* wr = lw + row * HID + part * 16;
            const float* os = x_s + part * 16;
            float acc = 0.f;
            #pragma unroll
            for (int k = 0; k < 16; ++k) acc = fmaf(wr[k], os[k], acc);
            acc += __shfl_xor(acc, 1);
            acc += __shfl_xor(acc, 2);
            acc += __shfl_xor(acc, 4);
            if (part == 0) Y[((size_t)step * BATCH + b) * 3 + row] = acc + lb[row];
        }
        __syncthreads();
    }
}

// ---------------------------------------------------------------------------
extern "C" void kernel_launch(void* const* d_in, const int* in_sizes, int n_in,
                              void* d_out, int out_size, void* d_ws, size_t ws_size,
                              hipStream_t stream) {
    const float* cnn        = (const float*)d_in[0];
    const float* eWih0      = (const float*)d_in[1];
    const float* eWhh0      = (const float*)d_in[2];
    const float* eb0        = (const float*)d_in[3];
    const float* eWih1      = (const float*)d_in[4];
    const float* eWhh1      = (const float*)d_in[5];
    const float* eb1        = (const float*)d_in[6];
    const float* attn_in_w  = (const float*)d_in[7];
    const float* attn_in_b  = (const float*)d_in[8];
    const float* attn_out_w = (const float*)d_in[9];
    const float* attn_out_b = (const float*)d_in[10];
    const float* dWih0      = (const float*)d_in[11];
    const float* dWhh0      = (const float*)d_in[12];
    const float* db0        = (const float*)d_in[13];
    const float* dWih1      = (const float*)d_in[14];
    const float* dWhh1      = (const float*)d_in[15];
    const float* db1        = (const float*)d_in[16];
    const float* lin_w      = (const float*)d_in[17];
    const float* lin_b      = (const float*)d_in[18];
    float* Y  = (float*)d_out;

    // ws: X (32768*512 f32) | Hb (32768*128 f32) | Kb | Vt | Wb2 | b0p
    float* ws = (float*)d_ws;
    float* X  = ws;                                  // 64 MiB (also KVf scratch)
    float* Hb = X + (size_t)32768 * 512;             // 16 MiB
    unsigned short* Kb  = (unsigned short*)(Hb + (size_t)32768 * 128);  // 8 MiB
    unsigned short* Vt  = Kb + (size_t)BATCH * T_LEN * HID;             // 8 MiB
    unsigned short* Wb2 = Vt + (size_t)BATCH * HID * T_LEN;             // 688 KiB
    float* b0p  = (float*)(Wb2 + W2_TOTAL);                             // 2 KiB

    const int M = T_LEN * BATCH;  // 32768

    hipFuncSetAttribute((const void*)decoder5,
                        hipFuncAttributeMaxDynamicSharedMemorySize, 131072);

    // decoder weight prep (tiny)
    pack2<<<(W2_TOTAL + 255) / 256, 256, 0, stream>>>(attn_in_w, dWih0, dWhh0, dWih1, dWhh1, Wb2);
    fuse_wxc<<<256, 256, 0, stream>>>(dWih0, attn_out_w, Wb2);
    fuse_b0<<<4, 128, 0, stream>>>(dWih0, attn_out_b, db0, b0p);

    // encoder layer 0
    gemm_bias<<<dim3(4, M/128), 256, 0, stream>>>(cnn, eWih0, eb0, X, M, 512, 1024);
    lstm_rec<<<BATCH, 512, 0, stream>>>(X, eWhh0, Hb);
    // encoder layer 1
    gemm_bias<<<dim3(4, M/128), 256, 0, stream>>>(Hb, eWih1, eb1, X, M, 512, 128);
    lstm_rec<<<BATCH, 512, 0, stream>>>(X, eWhh1, Hb);   // Hb = enc
    // KV = enc @ [Wk;Wv]^T + [bk;bv]  -> fp32 scratch in X
    gemm_bias<<<dim3(2, M/128), 256, 0, stream>>>(Hb, attn_in_w + 128*128, attn_in_b + 128,
                                                  X, M, 256, 128);
    kv_pack<<<256, 256, 0, stream>>>(X, Kb, Vt);
    // decoder: per-batch, weights in VGPRs, no grid sync
    decoder5<<<BATCH, 1024, 131072, stream>>>(Kb, Vt, Wb2, b0p,
                                              attn_in_b, db1, lin_w, lin_b, Y);
}